// Round 1
// baseline (564.272 us; speedup 1.0000x reference)
//
#include <hip/hip_runtime.h>
#include <hip/hip_bf16.h>

// Fused attention block: qkv = x@Wqkv+b; attn; out = attn_out@Wfc+b
// B=2, N=4096, DIM=1024, H=16, D=64. All GEMM/attn math in bf16 MFMA, fp32 accum.
//
// Workspace layout (bytes):
//   xb     @ 0         (16,777,216)  x cast to bf16           (8192 x 1024)
//   wqkvt  @ 16777216  ( 6,291,456)  Wqkv^T bf16              (3072 x 1024)
//   wfct   @ 23068672  ( 2,097,152)  Wfc^T bf16               (1024 x 1024)
//   q      @ 25165824  (16,777,216)  (B,H,N,D) bf16
//   k      @ 41943040  (16,777,216)  (B,H,N,D) bf16
//   v      @ 58720256  (16,777,216)  (B,H,N,D) bf16
//   vt     @ 75497472  (16,777,216)  (B,H,D,N) bf16
//   ao     @ 92274688  (16,777,216)  attn out (B*N, DIM) bf16
// total ~109 MB

#define SEQ   4096
#define NHEAD 16
#define HDIM  64
#define FDIM  1024
#define BATCH 2
#define MTOT  (BATCH * SEQ)       // 8192
#define ATTN_SCALE 0.125f

typedef __attribute__((ext_vector_type(8))) __bf16 bf16x8;
typedef __attribute__((ext_vector_type(4))) __bf16 bf16x4;
typedef __attribute__((ext_vector_type(4))) float  f32x4;

__device__ __forceinline__ f32x4 mfma16(bf16x8 a, bf16x8 b, f32x4 c) {
    return __builtin_amdgcn_mfma_f32_16x16x32_bf16(a, b, c, 0, 0, 0);
}

// ---------------- cast x: fp32 -> bf16 ----------------
__global__ __launch_bounds__(256) void cast_x_kernel(const float* __restrict__ in,
                                                     __bf16* __restrict__ out, int n4) {
    int i = blockIdx.x * 256 + threadIdx.x;
    if (i < n4) {
        f32x4 v = reinterpret_cast<const f32x4*>(in)[i];
        bf16x4 o;
        #pragma unroll
        for (int j = 0; j < 4; ++j) o[j] = (__bf16)v[j];
        reinterpret_cast<bf16x4*>(out)[i] = o;
    }
}

// ---------------- transpose + cast W: (K x N) fp32 -> (N x K) bf16 ----------------
__global__ __launch_bounds__(256) void transpose_cast_kernel(const float* __restrict__ in,
                                                             __bf16* __restrict__ out,
                                                             int K, int N) {
    int nbk = K >> 6;
    int bn = blockIdx.x / nbk, bk = blockIdx.x % nbk;
    int n0 = bn * 64, k0 = bk * 64;
    __shared__ __bf16 tile[64][72];
    int t = threadIdx.x;
    #pragma unroll
    for (int p = 0; p < 4; ++p) {
        int c = t + p * 256;
        int kr = c >> 4, nc = (c & 15) * 4;
        f32x4 v = *reinterpret_cast<const f32x4*>(&in[(size_t)(k0 + kr) * N + n0 + nc]);
        #pragma unroll
        for (int j = 0; j < 4; ++j) tile[kr][nc + j] = (__bf16)v[j];
    }
    __syncthreads();
    #pragma unroll
    for (int p = 0; p < 2; ++p) {
        int c = t + p * 256;
        int nr = c >> 3, kc = (c & 7) * 8;
        bf16x8 o;
        #pragma unroll
        for (int j = 0; j < 8; ++j) o[j] = tile[kc + j][nr];
        *reinterpret_cast<bf16x8*>(&out[(size_t)(n0 + nr) * K + k0 + kc]) = o;
    }
}

// ---------------- transpose v: (B,H,N,D) -> (B,H,D,N) bf16 ----------------
__global__ __launch_bounds__(256) void transpose_v_kernel(const __bf16* __restrict__ v,
                                                          __bf16* __restrict__ vt) {
    int bh = blockIdx.x >> 6;
    int n0 = (blockIdx.x & 63) * 64;
    const __bf16* vp = v + (size_t)bh * SEQ * HDIM;
    __bf16* vtp = vt + (size_t)bh * SEQ * HDIM;
    __shared__ __bf16 tile[64][72];
    int t = threadIdx.x;
    #pragma unroll
    for (int p = 0; p < 2; ++p) {
        int c = t + p * 256;
        int r = c >> 3, dch = (c & 7) * 8;
        *reinterpret_cast<bf16x8*>(&tile[r][dch]) =
            *reinterpret_cast<const bf16x8*>(&vp[(size_t)(n0 + r) * HDIM + dch]);
    }
    __syncthreads();
    #pragma unroll
    for (int p = 0; p < 2; ++p) {
        int c = t + p * 256;
        int d = c >> 3, nch = (c & 7) * 8;
        bf16x8 o;
        #pragma unroll
        for (int j = 0; j < 8; ++j) o[j] = tile[nch + j][d];
        *reinterpret_cast<bf16x8*>(&vtp[(size_t)d * SEQ + n0 + nch]) = o;
    }
}

// ---------------- GEMM: C = A(MxK) * Bt(NxK)^T + bias ----------------
// MODE 0: scatter bf16 into q/k/v (out = q base; q,k,v contiguous)
// MODE 1: fp32 output row-major
template <int MODE>
__global__ __launch_bounds__(256) void gemm_bt_kernel(const __bf16* __restrict__ A,
                                                      const __bf16* __restrict__ Bt,
                                                      const float* __restrict__ bias,
                                                      void* __restrict__ out,
                                                      int M, int N, int K, int nbn) {
    int bm = blockIdx.x / nbn, bn = blockIdx.x % nbn;
    int m0 = bm * 128, n0 = bn * 128;
    __shared__ __bf16 As[128][40];
    __shared__ __bf16 Bs[128][40];
    int t = threadIdx.x, lane = t & 63, w = t >> 6;
    int wr = w >> 1, wc = w & 1;
    int l15 = lane & 15, lk = (lane >> 4) * 8;

    f32x4 acc[4][4] = {};

    for (int kt = 0; kt < K; kt += 32) {
        #pragma unroll
        for (int p = 0; p < 2; ++p) {
            int c = t + p * 256;
            int r = c >> 2, kc = (c & 3) * 8;
            *reinterpret_cast<bf16x8*>(&As[r][kc]) =
                *reinterpret_cast<const bf16x8*>(&A[(size_t)(m0 + r) * K + kt + kc]);
            *reinterpret_cast<bf16x8*>(&Bs[r][kc]) =
                *reinterpret_cast<const bf16x8*>(&Bt[(size_t)(n0 + r) * K + kt + kc]);
        }
        __syncthreads();
        bf16x8 af[4], bfv[4];
        #pragma unroll
        for (int fm = 0; fm < 4; ++fm)
            af[fm] = *reinterpret_cast<const bf16x8*>(&As[wr * 64 + fm * 16 + l15][lk]);
        #pragma unroll
        for (int fn = 0; fn < 4; ++fn)
            bfv[fn] = *reinterpret_cast<const bf16x8*>(&Bs[wc * 64 + fn * 16 + l15][lk]);
        #pragma unroll
        for (int fm = 0; fm < 4; ++fm)
            #pragma unroll
            for (int fn = 0; fn < 4; ++fn)
                acc[fm][fn] = mfma16(af[fm], bfv[fn], acc[fm][fn]);
        __syncthreads();
    }

    #pragma unroll
    for (int fn = 0; fn < 4; ++fn) {
        int col = n0 + wc * 64 + fn * 16 + l15;
        float bi = bias[col];
        #pragma unroll
        for (int fm = 0; fm < 4; ++fm) {
            f32x4 c = acc[fm][fn];
            #pragma unroll
            for (int r = 0; r < 4; ++r) {
                int row = m0 + wr * 64 + fm * 16 + (lane >> 4) * 4 + r;
                float val = c[r] + bi;
                if (MODE == 0) {
                    int sel = col >> 10, h = (col >> 6) & 15, d = col & 63;
                    int b = row >> 12, nr = row & 4095;
                    __bf16* qkv = (__bf16*)out;
                    qkv[(size_t)sel * (BATCH * NHEAD * SEQ * HDIM) +
                        ((size_t)(b * NHEAD + h) * SEQ + nr) * HDIM + d] = (__bf16)val;
                } else {
                    ((float*)out)[(size_t)row * N + col] = val;
                }
            }
        }
    }
}

// ---------------- flash attention ----------------
// grid: (B*H) * (SEQ/64) blocks; 256 threads = 4 waves, each wave owns 16 q rows.
__global__ __launch_bounds__(256) void attn_kernel(const __bf16* __restrict__ q,
                                                   const __bf16* __restrict__ k,
                                                   const __bf16* __restrict__ vt,
                                                   __bf16* __restrict__ ao) {
    int bh = blockIdx.x >> 6;
    int q0 = (blockIdx.x & 63) * 64;
    int b = bh >> 4, h = bh & 15;
    const __bf16* qp = q + (size_t)bh * SEQ * HDIM;
    const __bf16* kp = k + (size_t)bh * SEQ * HDIM;
    const __bf16* vtp = vt + (size_t)bh * SEQ * HDIM;

    __shared__ __bf16 Ks[64][72];   // K tile: [key][d]
    __shared__ __bf16 Vs[64][72];   // V^T tile: [d][key]
    __shared__ __bf16 Ps[4][16][72];// per-wave P strip: [qrow][key]

    int t = threadIdx.x, lane = t & 63, w = t >> 6;
    int l15 = lane & 15, lg = lane >> 4;

    // Q fragments for this wave's 16-row strip (A-operand layout)
    bf16x8 qf[2];
    #pragma unroll
    for (int kc = 0; kc < 2; ++kc)
        qf[kc] = *reinterpret_cast<const bf16x8*>(
            &qp[(size_t)(q0 + w * 16 + l15) * HDIM + kc * 32 + lg * 8]);

    f32x4 oacc[4] = {};
    float mrun[4], lrun[4];
    #pragma unroll
    for (int r = 0; r < 4; ++r) { mrun[r] = -1e30f; lrun[r] = 0.f; }

    for (int kt = 0; kt < SEQ; kt += 64) {
        // stage K tile and V^T tile
        #pragma unroll
        for (int p = 0; p < 2; ++p) {
            int c = t + p * 256;
            int r = c >> 3, dch = (c & 7) * 8;
            *reinterpret_cast<bf16x8*>(&Ks[r][dch]) =
                *reinterpret_cast<const bf16x8*>(&kp[(size_t)(kt + r) * HDIM + dch]);
            *reinterpret_cast<bf16x8*>(&Vs[r][dch]) =
                *reinterpret_cast<const bf16x8*>(&vtp[(size_t)r * SEQ + kt + dch]);
        }
        __syncthreads();

        // S = Q K^T (strip: 16 x 64)
        f32x4 s[4];
        #pragma unroll
        for (int fn = 0; fn < 4; ++fn) {
            bf16x8 b0 = *reinterpret_cast<const bf16x8*>(&Ks[fn * 16 + l15][lg * 8]);
            bf16x8 b1 = *reinterpret_cast<const bf16x8*>(&Ks[fn * 16 + l15][32 + lg * 8]);
            f32x4 z = {};
            z = mfma16(qf[0], b0, z);
            s[fn] = mfma16(qf[1], b1, z);
        }

        // online softmax (rows = lg*4 + r of the strip)
        #pragma unroll
        for (int r = 0; r < 4; ++r) {
            #pragma unroll
            for (int fn = 0; fn < 4; ++fn) s[fn][r] *= ATTN_SCALE;
            float mx = fmaxf(fmaxf(s[0][r], s[1][r]), fmaxf(s[2][r], s[3][r]));
            #pragma unroll
            for (int off = 1; off < 16; off <<= 1) mx = fmaxf(mx, __shfl_xor(mx, off, 16));
            float mnew = fmaxf(mrun[r], mx);
            float alpha = __expf(mrun[r] - mnew);
            float sum = 0.f;
            #pragma unroll
            for (int fn = 0; fn < 4; ++fn) {
                float pv = __expf(s[fn][r] - mnew);
                s[fn][r] = pv;
                sum += pv;
            }
            #pragma unroll
            for (int off = 1; off < 16; off <<= 1) sum += __shfl_xor(sum, off, 16);
            lrun[r] = lrun[r] * alpha + sum;
            mrun[r] = mnew;
            #pragma unroll
            for (int fd = 0; fd < 4; ++fd) oacc[fd][r] *= alpha;
        }

        // write P strip to per-wave LDS (bf16), C-layout -> A-layout redistribution
        #pragma unroll
        for (int fn = 0; fn < 4; ++fn)
            #pragma unroll
            for (int r = 0; r < 4; ++r)
                Ps[w][lg * 4 + r][fn * 16 + l15] = (__bf16)s[fn][r];
        // same-wave LDS RAW: DS ops complete in order within a wave; compiler orders them.

        // O += P V
        #pragma unroll
        for (int kc = 0; kc < 2; ++kc) {
            bf16x8 pf = *reinterpret_cast<const bf16x8*>(&Ps[w][l15][kc * 32 + lg * 8]);
            #pragma unroll
            for (int fd = 0; fd < 4; ++fd) {
                bf16x8 vf = *reinterpret_cast<const bf16x8*>(&Vs[fd * 16 + l15][kc * 32 + lg * 8]);
                oacc[fd] = mfma16(pf, vf, oacc[fd]);
            }
        }
        __syncthreads();
    }

    // epilogue: normalize and write (B, N, H*D) bf16
    #pragma unroll
    for (int fd = 0; fd < 4; ++fd) {
        int d = fd * 16 + l15;
        #pragma unroll
        for (int r = 0; r < 4; ++r) {
            int row = q0 + w * 16 + lg * 4 + r;
            float o = oacc[fd][r] / lrun[r];
            ao[((size_t)(b * SEQ + row)) * FDIM + h * HDIM + d] = (__bf16)o;
        }
    }
}

// ---------------- launcher ----------------
extern "C" void kernel_launch(void* const* d_in, const int* in_sizes, int n_in,
                              void* d_out, int out_size, void* d_ws, size_t ws_size,
                              hipStream_t stream) {
    const float* x    = (const float*)d_in[0];
    const float* Wqkv = (const float*)d_in[1];
    const float* bqkv = (const float*)d_in[2];
    const float* Wfc  = (const float*)d_in[3];
    const float* bfc  = (const float*)d_in[4];
    float* out = (float*)d_out;

    char* ws = (char*)d_ws;
    __bf16* xb    = (__bf16*)(ws + 0);
    __bf16* wqkvt = (__bf16*)(ws + 16777216);
    __bf16* wfct  = (__bf16*)(ws + 23068672);
    __bf16* qb    = (__bf16*)(ws + 25165824);
    __bf16* kb    = (__bf16*)(ws + 41943040);
    __bf16* vb    = (__bf16*)(ws + 58720256);
    __bf16* vtb   = (__bf16*)(ws + 75497472);
    __bf16* aob   = (__bf16*)(ws + 92274688);

    // prep: casts + weight transposes
    cast_x_kernel<<<8192, 256, 0, stream>>>(x, xb, (MTOT * FDIM) / 4);
    transpose_cast_kernel<<<(3 * FDIM / 64) * (FDIM / 64), 256, 0, stream>>>(Wqkv, wqkvt, FDIM, 3 * FDIM);
    transpose_cast_kernel<<<(FDIM / 64) * (FDIM / 64), 256, 0, stream>>>(Wfc, wfct, FDIM, FDIM);

    // qkv projection -> q,k,v (B,H,N,D)
    gemm_bt_kernel<0><<<(MTOT / 128) * (3 * FDIM / 128), 256, 0, stream>>>(
        xb, wqkvt, bqkv, (void*)qb, MTOT, 3 * FDIM, FDIM, 3 * FDIM / 128);

    // v -> v^T
    transpose_v_kernel<<<BATCH * NHEAD * (SEQ / 64), 256, 0, stream>>>(vb, vtb);

    // flash attention
    attn_kernel<<<BATCH * NHEAD * (SEQ / 64), 256, 0, stream>>>(qb, kb, vtb, aob);

    // output projection (fp32 out)
    gemm_bt_kernel<1><<<(MTOT / 128) * (FDIM / 128), 256, 0, stream>>>(
        aob, wfct, bfc, (void*)out, MTOT, FDIM, FDIM, FDIM / 128);
}

// Round 2
// 371.743 us; speedup vs baseline: 1.5179x; 1.5179x over previous
//
#include <hip/hip_runtime.h>
#include <hip/hip_bf16.h>

// Fused attention block: qkv = x@Wqkv+b; attn; out = attn_out@Wfc+b
// B=2, N=4096, DIM=1024, H=16, D=64. bf16 MFMA, fp32 accum.
//
// Workspace layout (bytes):
//   xb     @ 0         x bf16 (8192x1024)
//   wqkvt  @ 16777216  Wqkv^T bf16 (3072x1024)
//   wfct   @ 23068672  Wfc^T bf16 (1024x1024)
//   q      @ 25165824  (B,H,N,D) bf16  (pre-scaled by 0.125*log2e)
//   k      @ 41943040  (B,H,N,D) bf16
//   v      @ 58720256  (B,H,N,D) bf16
//   vt     @ 75497472  (B,H,D,N) bf16
//   ao     @ 92274688  attn out (B*N, DIM) bf16

#define SEQ   4096
#define NHEAD 16
#define HDIM  64
#define FDIM  1024
#define BATCH 2
#define MTOT  (BATCH * SEQ)
// 0.125 (1/sqrt(64)) * log2(e): folded into q so softmax runs in base-2 domain.
#define QSCALE 0.1803368801111204f

typedef __attribute__((ext_vector_type(8)))  __bf16 bf16x8;
typedef __attribute__((ext_vector_type(4)))  __bf16 bf16x4;
typedef __attribute__((ext_vector_type(2)))  __bf16 bf16x2;
typedef __attribute__((ext_vector_type(4)))  float  f32x4;
typedef __attribute__((ext_vector_type(16))) float  f32x16;
typedef __attribute__((ext_vector_type(2)))  unsigned uint2v;
typedef __attribute__((ext_vector_type(4)))  unsigned uint4v;

__device__ __forceinline__ f32x4 mfma16(bf16x8 a, bf16x8 b, f32x4 c) {
    return __builtin_amdgcn_mfma_f32_16x16x32_bf16(a, b, c, 0, 0, 0);
}
__device__ __forceinline__ f32x16 mfma32(bf16x8 a, bf16x8 b, f32x16 c) {
    return __builtin_amdgcn_mfma_f32_32x32x16_bf16(a, b, c, 0, 0, 0);
}
__device__ __forceinline__ unsigned packbf2(float lo, float hi) {
    bf16x2 t; t[0] = (__bf16)lo; t[1] = (__bf16)hi;
    return __builtin_bit_cast(unsigned, t);
}
__device__ __forceinline__ bf16x8 fragu(unsigned a, unsigned b, unsigned c, unsigned d) {
    uint4v u = {a, b, c, d};
    return __builtin_bit_cast(bf16x8, u);
}

// ---------------- cast x: fp32 -> bf16 ----------------
__global__ __launch_bounds__(256) void cast_x_kernel(const float* __restrict__ in,
                                                     __bf16* __restrict__ out, int n4) {
    int i = blockIdx.x * 256 + threadIdx.x;
    if (i < n4) {
        f32x4 v = reinterpret_cast<const f32x4*>(in)[i];
        bf16x4 o;
        #pragma unroll
        for (int j = 0; j < 4; ++j) o[j] = (__bf16)v[j];
        reinterpret_cast<bf16x4*>(out)[i] = o;
    }
}

// ---------------- transpose + cast W: (K x N) fp32 -> (N x K) bf16 ----------------
__global__ __launch_bounds__(256) void transpose_cast_kernel(const float* __restrict__ in,
                                                             __bf16* __restrict__ out,
                                                             int K, int N) {
    int nbk = K >> 6;
    int bn = blockIdx.x / nbk, bk = blockIdx.x % nbk;
    int n0 = bn * 64, k0 = bk * 64;
    __shared__ __bf16 tile[64][72];
    int t = threadIdx.x;
    #pragma unroll
    for (int p = 0; p < 4; ++p) {
        int c = t + p * 256;
        int kr = c >> 4, nc = (c & 15) * 4;
        f32x4 v = *reinterpret_cast<const f32x4*>(&in[(size_t)(k0 + kr) * N + n0 + nc]);
        #pragma unroll
        for (int j = 0; j < 4; ++j) tile[kr][nc + j] = (__bf16)v[j];
    }
    __syncthreads();
    #pragma unroll
    for (int p = 0; p < 2; ++p) {
        int c = t + p * 256;
        int nr = c >> 3, kc = (c & 7) * 8;
        bf16x8 o;
        #pragma unroll
        for (int j = 0; j < 8; ++j) o[j] = tile[kc + j][nr];
        *reinterpret_cast<bf16x8*>(&out[(size_t)(n0 + nr) * K + k0 + kc]) = o;
    }
}

// ---------------- transpose v: (B,H,N,D) -> (B,H,D,N) bf16 ----------------
__global__ __launch_bounds__(256) void transpose_v_kernel(const __bf16* __restrict__ v,
                                                          __bf16* __restrict__ vt) {
    int bh = blockIdx.x >> 6;
    int n0 = (blockIdx.x & 63) * 64;
    const __bf16* vp = v + (size_t)bh * SEQ * HDIM;
    __bf16* vtp = vt + (size_t)bh * SEQ * HDIM;
    __shared__ __bf16 tile[64][72];
    int t = threadIdx.x;
    #pragma unroll
    for (int p = 0; p < 2; ++p) {
        int c = t + p * 256;
        int r = c >> 3, dch = (c & 7) * 8;
        *reinterpret_cast<bf16x8*>(&tile[r][dch]) =
            *reinterpret_cast<const bf16x8*>(&vp[(size_t)(n0 + r) * HDIM + dch]);
    }
    __syncthreads();
    #pragma unroll
    for (int p = 0; p < 2; ++p) {
        int c = t + p * 256;
        int d = c >> 3, nch = (c & 7) * 8;
        bf16x8 o;
        #pragma unroll
        for (int j = 0; j < 8; ++j) o[j] = tile[nch + j][d];
        *reinterpret_cast<bf16x8*>(&vtp[(size_t)d * SEQ + n0 + nch]) = o;
    }
}

// ---------------- GEMM: C = A(MxK) * Bt(NxK)^T + bias ----------------
// MODE 0: scatter bf16 into q/k/v; q gets pre-scaled by QSCALE.
// MODE 1: fp32 output row-major
template <int MODE>
__global__ __launch_bounds__(256) void gemm_bt_kernel(const __bf16* __restrict__ A,
                                                      const __bf16* __restrict__ Bt,
                                                      const float* __restrict__ bias,
                                                      void* __restrict__ out,
                                                      int M, int N, int K, int nbn) {
    int bm = blockIdx.x / nbn, bn = blockIdx.x % nbn;
    int m0 = bm * 128, n0 = bn * 128;
    __shared__ __bf16 As[128][40];
    __shared__ __bf16 Bs[128][40];
    int t = threadIdx.x, lane = t & 63, w = t >> 6;
    int wr = w >> 1, wc = w & 1;
    int l15 = lane & 15, lk = (lane >> 4) * 8;

    f32x4 acc[4][4] = {};

    for (int kt = 0; kt < K; kt += 32) {
        #pragma unroll
        for (int p = 0; p < 2; ++p) {
            int c = t + p * 256;
            int r = c >> 2, kc = (c & 3) * 8;
            *reinterpret_cast<bf16x8*>(&As[r][kc]) =
                *reinterpret_cast<const bf16x8*>(&A[(size_t)(m0 + r) * K + kt + kc]);
            *reinterpret_cast<bf16x8*>(&Bs[r][kc]) =
                *reinterpret_cast<const bf16x8*>(&Bt[(size_t)(n0 + r) * K + kt + kc]);
        }
        __syncthreads();
        bf16x8 af[4], bfv[4];
        #pragma unroll
        for (int fm = 0; fm < 4; ++fm)
            af[fm] = *reinterpret_cast<const bf16x8*>(&As[wr * 64 + fm * 16 + l15][lk]);
        #pragma unroll
        for (int fn = 0; fn < 4; ++fn)
            bfv[fn] = *reinterpret_cast<const bf16x8*>(&Bs[wc * 64 + fn * 16 + l15][lk]);
        #pragma unroll
        for (int fm = 0; fm < 4; ++fm)
            #pragma unroll
            for (int fn = 0; fn < 4; ++fn)
                acc[fm][fn] = mfma16(af[fm], bfv[fn], acc[fm][fn]);
        __syncthreads();
    }

    #pragma unroll
    for (int fn = 0; fn < 4; ++fn) {
        int col = n0 + wc * 64 + fn * 16 + l15;
        float bi = bias[col];
        #pragma unroll
        for (int fm = 0; fm < 4; ++fm) {
            f32x4 c = acc[fm][fn];
            #pragma unroll
            for (int r = 0; r < 4; ++r) {
                int row = m0 + wr * 64 + fm * 16 + (lane >> 4) * 4 + r;
                float val = c[r] + bi;
                if (MODE == 0) {
                    int sel = col >> 10, h = (col >> 6) & 15, d = col & 63;
                    int b = row >> 12, nr = row & 4095;
                    if (sel == 0) val *= QSCALE;   // fold attn scale + log2e into q
                    __bf16* qkv = (__bf16*)out;
                    qkv[(size_t)sel * (BATCH * NHEAD * SEQ * HDIM) +
                        ((size_t)(b * NHEAD + h) * SEQ + nr) * HDIM + d] = (__bf16)val;
                } else {
                    ((float*)out)[(size_t)row * N + col] = val;
                }
            }
        }
    }
}

// ---------------- flash attention, 8-warp-style 32x32 structure ----------------
// grid: (B*H) * (SEQ/256) blocks; 256 threads = 4 waves; each wave owns 64 q rows
// (2 sub-blocks of 32). Swapped QK^T: S'[key][q] = mfma32(A=K, B=Q) so each lane
// owns one q column; softmax is register-reduce + 1 shfl_xor(32). P goes to the
// PV A-operand fully in-register via bf16 pack + permlane32_swap (T12).
// K/V LDS tiles are XOR-swizzled (T2): byte ^= (row&7)<<4 on 128B rows.
__global__ __launch_bounds__(256, 2) void attn_kernel(const __bf16* __restrict__ q,
                                                      const __bf16* __restrict__ k,
                                                      const __bf16* __restrict__ vt,
                                                      __bf16* __restrict__ ao) {
    const int bh = blockIdx.x >> 4;
    const int q0 = (blockIdx.x & 15) * 256;
    const int b = bh >> 4, h = bh & 15;
    const __bf16* __restrict__ qp = q + (size_t)bh * SEQ * HDIM;
    const __bf16* __restrict__ kp = k + (size_t)bh * SEQ * HDIM;
    const __bf16* __restrict__ vtp = vt + (size_t)bh * SEQ * HDIM;

    __shared__ __bf16 Ks[64 * 64];   // [key][d], swizzled
    __shared__ __bf16 Vs[64 * 64];   // [d][key], swizzled

    const int t = threadIdx.x, lane = t & 63, w = t >> 6;
    const int l31 = lane & 31, hi = lane >> 5;

    // Q fragments (B-operand): lane holds Q[q0+w*64+qb*32+l31][c*16+hi*8 .. +8]
    bf16x8 qf[2][4];
    #pragma unroll
    for (int qb = 0; qb < 2; ++qb)
        #pragma unroll
        for (int c = 0; c < 4; ++c)
            qf[qb][c] = *reinterpret_cast<const bf16x8*>(
                &qp[(size_t)(q0 + w * 64 + qb * 32 + l31) * HDIM + c * 16 + hi * 8]);

    f32x16 oacc[2][2];
    #pragma unroll
    for (int i = 0; i < 2; ++i)
        #pragma unroll
        for (int j = 0; j < 2; ++j)
            #pragma unroll
            for (int r = 0; r < 16; ++r) oacc[i][j][r] = 0.f;

    float mrun[2] = {-1e30f, -1e30f};
    float lrun[2] = {0.f, 0.f};

    // staging: thread t stages rows r0 and r0+32, 16B chunk hw, of both tiles
    const int r0 = t >> 3, hw = t & 7;
    const int colsw = (hw * 16) ^ ((r0 & 7) << 4);
    const int ldsA0 = r0 * 128 + colsw;
    const int ldsA1 = (r0 + 32) * 128 + colsw;       // (r0+32)&7 == r0&7
    const size_t gK0 = (size_t)r0 * HDIM + hw * 8;
    const size_t gK1 = (size_t)(r0 + 32) * HDIM + hw * 8;
    const size_t gV0 = (size_t)r0 * SEQ + hw * 8;
    const size_t gV1 = (size_t)(r0 + 32) * SEQ + hw * 8;
    const int kread = (l31 & 7) << 4;                // read-side row-XOR

    bf16x8 kr0 = *reinterpret_cast<const bf16x8*>(kp + gK0);
    bf16x8 kr1 = *reinterpret_cast<const bf16x8*>(kp + gK1);
    bf16x8 vr0 = *reinterpret_cast<const bf16x8*>(vtp + gV0);
    bf16x8 vr1 = *reinterpret_cast<const bf16x8*>(vtp + gV1);

    for (int kt = 0; kt < SEQ; kt += 64) {
        __syncthreads();    // previous tile's readers done
        *reinterpret_cast<bf16x8*>(reinterpret_cast<char*>(Ks) + ldsA0) = kr0;
        *reinterpret_cast<bf16x8*>(reinterpret_cast<char*>(Ks) + ldsA1) = kr1;
        *reinterpret_cast<bf16x8*>(reinterpret_cast<char*>(Vs) + ldsA0) = vr0;
        *reinterpret_cast<bf16x8*>(reinterpret_cast<char*>(Vs) + ldsA1) = vr1;
        if (kt + 64 < SEQ) {  // async-stage (T14): issue next-tile loads before compute
            const __bf16* kn = kp + (size_t)(kt + 64) * HDIM;
            const __bf16* vn = vtp + (kt + 64);
            kr0 = *reinterpret_cast<const bf16x8*>(kn + gK0);
            kr1 = *reinterpret_cast<const bf16x8*>(kn + gK1);
            vr0 = *reinterpret_cast<const bf16x8*>(vn + gV0);
            vr1 = *reinterpret_cast<const bf16x8*>(vn + gV1);
        }
        __syncthreads();    // staged tile visible

        #pragma unroll
        for (int qb = 0; qb < 2; ++qb) {
            // ---- QK^T (swapped): s[key][q], lane owns q=l31, keys crow(r,hi) ----
            f32x16 s0, s1;
            #pragma unroll
            for (int r = 0; r < 16; ++r) { s0[r] = 0.f; s1[r] = 0.f; }
            #pragma unroll
            for (int c = 0; c < 4; ++c) {
                const int co = (c * 32 + hi * 16) ^ kread;
                bf16x8 k0 = *reinterpret_cast<const bf16x8*>(
                    reinterpret_cast<char*>(Ks) + l31 * 128 + co);
                bf16x8 k1 = *reinterpret_cast<const bf16x8*>(
                    reinterpret_cast<char*>(Ks) + (32 + l31) * 128 + co);
                s0 = mfma32(k0, qf[qb][c], s0);
                s1 = mfma32(k1, qf[qb][c], s1);
            }

            // ---- online softmax (base-2 domain; scale pre-folded into q) ----
            float m0 = fmaxf(fmaxf(s0[0], s0[1]), fmaxf(s0[2], s0[3]));
            float m1 = fmaxf(fmaxf(s0[4], s0[5]), fmaxf(s0[6], s0[7]));
            float m2 = fmaxf(fmaxf(s0[8], s0[9]), fmaxf(s0[10], s0[11]));
            float m3 = fmaxf(fmaxf(s0[12], s0[13]), fmaxf(s0[14], s0[15]));
            float m4 = fmaxf(fmaxf(s1[0], s1[1]), fmaxf(s1[2], s1[3]));
            float m5 = fmaxf(fmaxf(s1[4], s1[5]), fmaxf(s1[6], s1[7]));
            float m6 = fmaxf(fmaxf(s1[8], s1[9]), fmaxf(s1[10], s1[11]));
            float m7 = fmaxf(fmaxf(s1[12], s1[13]), fmaxf(s1[14], s1[15]));
            float mx = fmaxf(fmaxf(fmaxf(m0, m1), fmaxf(m2, m3)),
                             fmaxf(fmaxf(m4, m5), fmaxf(m6, m7)));
            mx = fmaxf(mx, __shfl_xor(mx, 32));   // other 32 keys (paired lane)

            // defer-max (T13): rescale only when tile max grew > 8 (P bounded by 2^8)
            if (!__all(mx - mrun[qb] <= 8.0f)) {
                float mnew = fmaxf(mrun[qb], mx);
                float alpha = __builtin_exp2f(mrun[qb] - mnew);
                mrun[qb] = mnew;
                lrun[qb] *= alpha;
                #pragma unroll
                for (int r = 0; r < 16; ++r) {
                    int row = (r & 3) + 8 * (r >> 2) + 4 * hi;   // O-row this reg holds
                    float ar = __shfl(alpha, row);               // alpha lives at lane==q
                    oacc[qb][0][r] *= ar;
                    oacc[qb][1][r] *= ar;
                }
            }
            const float m = mrun[qb];
            float p[32];
            float ps = 0.f;
            #pragma unroll
            for (int r = 0; r < 16; ++r) p[r] = __builtin_exp2f(s0[r] - m);
            #pragma unroll
            for (int r = 0; r < 16; ++r) p[16 + r] = __builtin_exp2f(s1[r] - m);
            #pragma unroll
            for (int r = 0; r < 32; ++r) ps += p[r];
            lrun[qb] += ps;   // partial (own 32 keys); pair-summed in epilogue

            // ---- P -> PV A-frags in-register (pack + permlane32_swap) ----
            bf16x8 pa[4];
            #pragma unroll
            for (int kb = 0; kb < 2; ++kb) {
                unsigned pk0 = packbf2(p[kb * 16 + 0],  p[kb * 16 + 1]);
                unsigned pk1 = packbf2(p[kb * 16 + 2],  p[kb * 16 + 3]);
                unsigned pk2 = packbf2(p[kb * 16 + 4],  p[kb * 16 + 5]);
                unsigned pk3 = packbf2(p[kb * 16 + 6],  p[kb * 16 + 7]);
                unsigned pk4 = packbf2(p[kb * 16 + 8],  p[kb * 16 + 9]);
                unsigned pk5 = packbf2(p[kb * 16 + 10], p[kb * 16 + 11]);
                unsigned pk6 = packbf2(p[kb * 16 + 12], p[kb * 16 + 13]);
                unsigned pk7 = packbf2(p[kb * 16 + 14], p[kb * 16 + 15]);
                uint2v sA = __builtin_amdgcn_permlane32_swap(pk0, pk2, false, false);
                uint2v sB = __builtin_amdgcn_permlane32_swap(pk1, pk3, false, false);
                uint2v sC = __builtin_amdgcn_permlane32_swap(pk4, pk6, false, false);
                uint2v sD = __builtin_amdgcn_permlane32_swap(pk5, pk7, false, false);
                pa[kb * 2 + 0] = fragu(sA[0], sB[0], sA[1], sB[1]);
                pa[kb * 2 + 1] = fragu(sC[0], sD[0], sC[1], sD[1]);
            }

            // ---- O += P V : D[q][d], A=P (rows=q), B=Vt (rows=d) ----
            #pragma unroll
            for (int db = 0; db < 2; ++db) {
                #pragma unroll
                for (int kc = 0; kc < 4; ++kc) {
                    const int co = (kc * 32 + hi * 16) ^ kread;
                    bf16x8 vf = *reinterpret_cast<const bf16x8*>(
                        reinterpret_cast<char*>(Vs) + (db * 32 + l31) * 128 + co);
                    oacc[qb][db] = mfma32(pa[kc], vf, oacc[qb][db]);
                }
            }
        }
    }

    // ---- epilogue: combine pair-sums, normalize, store (B,N,H*D) bf16 ----
    #pragma unroll
    for (int qb = 0; qb < 2; ++qb) {
        float lt = lrun[qb] + __shfl_xor(lrun[qb], 32);
        #pragma unroll
        for (int r = 0; r < 16; ++r) {
            int row = (r & 3) + 8 * (r >> 2) + 4 * hi;
            float li = 1.0f / __shfl(lt, row);
            int qrow = q0 + w * 64 + qb * 32 + row;
            #pragma unroll
            for (int db = 0; db < 2; ++db) {
                int d = h * 64 + db * 32 + l31;
                ao[((size_t)(b * SEQ + qrow)) * FDIM + d] = (__bf16)(oacc[qb][db][r] * li);
            }
        }
    }
}

// ---------------- launcher ----------------
extern "C" void kernel_launch(void* const* d_in, const int* in_sizes, int n_in,
                              void* d_out, int out_size, void* d_ws, size_t ws_size,
                              hipStream_t stream) {
    const float* x    = (const float*)d_in[0];
    const float* Wqkv = (const float*)d_in[1];
    const float* bqkv = (const float*)d_in[2];
    const float* Wfc  = (const float*)d_in[3];
    const float* bfc  = (const float*)d_in[4];
    float* out = (float*)d_out;

    char* ws = (char*)d_ws;
    __bf16* xb    = (__bf16*)(ws + 0);
    __bf16* wqkvt = (__bf16*)(ws + 16777216);
    __bf16* wfct  = (__bf16*)(ws + 23068672);
    __bf16* qb    = (__bf16*)(ws + 25165824);
    __bf16* kb    = (__bf16*)(ws + 41943040);
    __bf16* vb    = (__bf16*)(ws + 58720256);
    __bf16* vtb   = (__bf16*)(ws + 75497472);
    __bf16* aob   = (__bf16*)(ws + 92274688);

    cast_x_kernel<<<8192, 256, 0, stream>>>(x, xb, (MTOT * FDIM) / 4);
    transpose_cast_kernel<<<(3 * FDIM / 64) * (FDIM / 64), 256, 0, stream>>>(Wqkv, wqkvt, FDIM, 3 * FDIM);
    transpose_cast_kernel<<<(FDIM / 64) * (FDIM / 64), 256, 0, stream>>>(Wfc, wfct, FDIM, FDIM);

    gemm_bt_kernel<0><<<(MTOT / 128) * (3 * FDIM / 128), 256, 0, stream>>>(
        xb, wqkvt, bqkv, (void*)qb, MTOT, 3 * FDIM, FDIM, 3 * FDIM / 128);

    transpose_v_kernel<<<BATCH * NHEAD * (SEQ / 64), 256, 0, stream>>>(vb, vtb);

    attn_kernel<<<BATCH * NHEAD * (SEQ / 256), 256, 0, stream>>>(qb, kb, vtb, aob);

    gemm_bt_kernel<1><<<(MTOT / 128) * (FDIM / 128), 256, 0, stream>>>(
        aob, wfct, bfc, (void*)out, MTOT, FDIM, FDIM, FDIM / 128);
}

// Round 3
// 324.774 us; speedup vs baseline: 1.7374x; 1.1446x over previous
//
#include <hip/hip_runtime.h>
#include <hip/hip_bf16.h>

// Fused attention block: qkv = x@Wqkv+b; attn; out = attn_out@Wfc+b
// B=2, N=4096, DIM=1024, H=16, D=64. bf16 MFMA, fp32 accum.

#define SEQ   4096
#define NHEAD 16
#define HDIM  64
#define FDIM  1024
#define BATCH 2
#define MTOT  (BATCH * SEQ)
// 0.125 (1/sqrt(64)) * log2(e): folded into q so softmax runs in base-2 domain.
#define QSCALE 0.1803368801111204f

typedef __attribute__((ext_vector_type(8)))  __bf16 bf16x8;
typedef __attribute__((ext_vector_type(4)))  __bf16 bf16x4;
typedef __attribute__((ext_vector_type(2)))  __bf16 bf16x2;
typedef __attribute__((ext_vector_type(4)))  float  f32x4;
typedef __attribute__((ext_vector_type(16))) float  f32x16;
typedef __attribute__((ext_vector_type(2)))  unsigned uint2v;
typedef __attribute__((ext_vector_type(4)))  unsigned uint4v;

__device__ __forceinline__ f32x4 mfma16(bf16x8 a, bf16x8 b, f32x4 c) {
    return __builtin_amdgcn_mfma_f32_16x16x32_bf16(a, b, c, 0, 0, 0);
}
__device__ __forceinline__ f32x16 mfma32(bf16x8 a, bf16x8 b, f32x16 c) {
    return __builtin_amdgcn_mfma_f32_32x32x16_bf16(a, b, c, 0, 0, 0);
}
__device__ __forceinline__ unsigned packbf2(float lo, float hi) {
    bf16x2 t; t[0] = (__bf16)lo; t[1] = (__bf16)hi;
    return __builtin_bit_cast(unsigned, t);
}
__device__ __forceinline__ bf16x8 fragu(unsigned a, unsigned b, unsigned c, unsigned d) {
    uint4v u = {a, b, c, d};
    return __builtin_bit_cast(bf16x8, u);
}
// raw v_exp_f32: 1 instruction (no denormal-safe expansion)
__device__ __forceinline__ float fexp2(float x) {
    float r; asm("v_exp_f32 %0, %1" : "=v"(r) : "v"(x)); return r;
}
// async global->LDS, 16B/lane; lds must be wave-uniform base (HW adds lane*16)
__device__ __forceinline__ void gload16(const void* g, void* l) {
    __builtin_amdgcn_global_load_lds(
        (const __attribute__((address_space(1))) unsigned*)g,
        (__attribute__((address_space(3))) unsigned*)l, 16, 0, 0);
}
__device__ __forceinline__ float fmax3(float a, float b, float c) {
    return fmaxf(fmaxf(a, b), c);   // clang fuses to v_max3_f32
}

// ---------------- cast x: fp32 -> bf16 ----------------
__global__ __launch_bounds__(256) void cast_x_kernel(const float* __restrict__ in,
                                                     __bf16* __restrict__ out, int n4) {
    int i = blockIdx.x * 256 + threadIdx.x;
    if (i < n4) {
        f32x4 v = reinterpret_cast<const f32x4*>(in)[i];
        bf16x4 o;
        #pragma unroll
        for (int j = 0; j < 4; ++j) o[j] = (__bf16)v[j];
        reinterpret_cast<bf16x4*>(out)[i] = o;
    }
}

// ---------------- transpose + cast W: (K x N) fp32 -> (N x K) bf16 ----------------
__global__ __launch_bounds__(256) void transpose_cast_kernel(const float* __restrict__ in,
                                                             __bf16* __restrict__ out,
                                                             int K, int N) {
    int nbk = K >> 6;
    int bn = blockIdx.x / nbk, bk = blockIdx.x % nbk;
    int n0 = bn * 64, k0 = bk * 64;
    __shared__ __bf16 tile[64][72];
    int t = threadIdx.x;
    #pragma unroll
    for (int p = 0; p < 4; ++p) {
        int c = t + p * 256;
        int kr = c >> 4, nc = (c & 15) * 4;
        f32x4 v = *reinterpret_cast<const f32x4*>(&in[(size_t)(k0 + kr) * N + n0 + nc]);
        #pragma unroll
        for (int j = 0; j < 4; ++j) tile[kr][nc + j] = (__bf16)v[j];
    }
    __syncthreads();
    #pragma unroll
    for (int p = 0; p < 2; ++p) {
        int c = t + p * 256;
        int nr = c >> 3, kc = (c & 7) * 8;
        bf16x8 o;
        #pragma unroll
        for (int j = 0; j < 8; ++j) o[j] = tile[kc + j][nr];
        *reinterpret_cast<bf16x8*>(&out[(size_t)(n0 + nr) * K + k0 + kc]) = o;
    }
}

// ---------------- transpose v: (B,H,N,D) -> (B,H,D,N) bf16 ----------------
__global__ __launch_bounds__(256) void transpose_v_kernel(const __bf16* __restrict__ v,
                                                          __bf16* __restrict__ vt) {
    int bh = blockIdx.x >> 6;
    int n0 = (blockIdx.x & 63) * 64;
    const __bf16* vp = v + (size_t)bh * SEQ * HDIM;
    __bf16* vtp = vt + (size_t)bh * SEQ * HDIM;
    __shared__ __bf16 tile[64][72];
    int t = threadIdx.x;
    #pragma unroll
    for (int p = 0; p < 2; ++p) {
        int c = t + p * 256;
        int r = c >> 3, dch = (c & 7) * 8;
        *reinterpret_cast<bf16x8*>(&tile[r][dch]) =
            *reinterpret_cast<const bf16x8*>(&vp[(size_t)(n0 + r) * HDIM + dch]);
    }
    __syncthreads();
    #pragma unroll
    for (int p = 0; p < 2; ++p) {
        int c = t + p * 256;
        int d = c >> 3, nch = (c & 7) * 8;
        bf16x8 o;
        #pragma unroll
        for (int j = 0; j < 8; ++j) o[j] = tile[nch + j][d];
        *reinterpret_cast<bf16x8*>(&vtp[(size_t)d * SEQ + n0 + nch]) = o;
    }
}

// ---------------- GEMM: C = A(MxK) * Bt(NxK)^T + bias (m97-style staging) ----------------
// MODE 0: scatter bf16 into q/k/v; q gets pre-scaled by QSCALE.
// MODE 1: fp32 output row-major
template <int MODE>
__global__ __launch_bounds__(256) void gemm_bt_kernel(const __bf16* __restrict__ A,
                                                      const __bf16* __restrict__ Bt,
                                                      const float* __restrict__ bias,
                                                      void* __restrict__ out,
                                                      int M, int N, int K, int nbn) {
    int bm = blockIdx.x / nbn, bn = blockIdx.x % nbn;
    int m0 = bm * 128, n0 = bn * 128;
    __shared__ __bf16 As[128 * 32];
    __shared__ __bf16 Bs[128 * 32];
    int t = threadIdx.x, lane = t & 63, w = t >> 6;
    int wr = w >> 1, wc = w & 1;
    int l15 = lane & 15, lk = (lane >> 4) * 8;

    f32x4 acc[4][4] = {};

    // staging geometry: chunk c = p*256 + t; row = c>>2; 8-elem chunk (c&3)
    const int r_c0 = t >> 2, kc_c0 = (t & 3) * 8;          // p=0
    const int r_c1 = (256 + t) >> 2, kc_c1 = (t & 3) * 8;  // p=1 (t&3 unchanged)
    char* AsB = (char*)As; char* BsB = (char*)Bs;
    const int lds0 = w * 1024;          // wave-uniform, p=0
    const int lds1 = 4096 + w * 1024;   // p=1

    for (int kt = 0; kt < K; kt += 32) {
        __syncthreads();
        gload16(&A[(size_t)(m0 + r_c0) * K + kt + kc_c0], AsB + lds0);
        gload16(&A[(size_t)(m0 + r_c1) * K + kt + kc_c1], AsB + lds1);
        gload16(&Bt[(size_t)(n0 + r_c0) * K + kt + kc_c0], BsB + lds0);
        gload16(&Bt[(size_t)(n0 + r_c1) * K + kt + kc_c1], BsB + lds1);
        __syncthreads();
        bf16x8 af[4], bfv[4];
        #pragma unroll
        for (int fm = 0; fm < 4; ++fm)
            af[fm] = *reinterpret_cast<const bf16x8*>(&As[(wr * 64 + fm * 16 + l15) * 32 + lk]);
        #pragma unroll
        for (int fn = 0; fn < 4; ++fn)
            bfv[fn] = *reinterpret_cast<const bf16x8*>(&Bs[(wc * 64 + fn * 16 + l15) * 32 + lk]);
        #pragma unroll
        for (int fm = 0; fm < 4; ++fm)
            #pragma unroll
            for (int fn = 0; fn < 4; ++fn)
                acc[fm][fn] = mfma16(af[fm], bfv[fn], acc[fm][fn]);
    }

    #pragma unroll
    for (int fn = 0; fn < 4; ++fn) {
        int col = n0 + wc * 64 + fn * 16 + l15;
        float bi = bias[col];
        #pragma unroll
        for (int fm = 0; fm < 4; ++fm) {
            f32x4 c = acc[fm][fn];
            #pragma unroll
            for (int r = 0; r < 4; ++r) {
                int row = m0 + wr * 64 + fm * 16 + (lane >> 4) * 4 + r;
                float val = c[r] + bi;
                if (MODE == 0) {
                    int sel = col >> 10, h = (col >> 6) & 15, d = col & 63;
                    int b = row >> 12, nr = row & 4095;
                    if (sel == 0) val *= QSCALE;   // fold attn scale + log2e into q
                    __bf16* qkv = (__bf16*)out;
                    qkv[(size_t)sel * (BATCH * NHEAD * SEQ * HDIM) +
                        ((size_t)(b * NHEAD + h) * SEQ + nr) * HDIM + d] = (__bf16)val;
                } else {
                    ((float*)out)[(size_t)row * N + col] = val;
                }
            }
        }
    }
}

// ---------------- flash attention ----------------
// grid: (B*H) * (SEQ/128); 256 threads = 4 waves; each wave owns 32 q rows.
// Swapped QK^T (lane owns q col), in-register P via pack+permlane32_swap,
// denominator via ones-MFMA, K/V double-buffered via global_load_lds with
// pre-swizzled global source (linear LDS dest, XOR-swizzled reads).
__global__ __launch_bounds__(256, 3) void attn_kernel(const __bf16* __restrict__ q,
                                                      const __bf16* __restrict__ k,
                                                      const __bf16* __restrict__ vt,
                                                      __bf16* __restrict__ ao) {
    const int bh = blockIdx.x >> 5;
    const int q0 = (blockIdx.x & 31) * 128;
    const int b = bh >> 4, h = bh & 15;
    const __bf16* __restrict__ qp = q + (size_t)bh * SEQ * HDIM;
    const __bf16* __restrict__ kp = k + (size_t)bh * SEQ * HDIM;
    const __bf16* __restrict__ vtp = vt + (size_t)bh * SEQ * HDIM;

    __shared__ __bf16 Ks[2][64 * 64];   // [buf][key][d], 8KB each
    __shared__ __bf16 Vs[2][64 * 64];   // [buf][d][key]

    const int t = threadIdx.x, lane = t & 63, w = t >> 6;
    const int l31 = lane & 31, hi = lane >> 5;

    // Q fragments (B-operand): lane holds Q[q0+w*32+l31][c*16+hi*8 .. +8]
    bf16x8 qf[4];
    #pragma unroll
    for (int c = 0; c < 4; ++c)
        qf[c] = *reinterpret_cast<const bf16x8*>(
            &qp[(size_t)(q0 + w * 32 + l31) * HDIM + c * 16 + hi * 8]);

    f32x16 oacc[2], lacc;
    #pragma unroll
    for (int r = 0; r < 16; ++r) { oacc[0][r] = 0.f; oacc[1][r] = 0.f; lacc[r] = 0.f; }
    float mrun = -1e30f;

    // ones B-fragment for row-sum MFMA (bf16 1.0 = 0x3F80)
    const uint4v onesu = {0x3F803F80u, 0x3F803F80u, 0x3F803F80u, 0x3F803F80u};
    const bf16x8 onesf = __builtin_bit_cast(bf16x8, onesu);

    // staging: thread t covers row r0 (and r0+32), pre-swizzled 16B chunk
    const int r0 = t >> 3, hw = t & 7;
    const int hwsw = (hw ^ (r0 & 7)) * 8;                 // swizzled source chunk (elems)
    const size_t gK0 = (size_t)r0 * HDIM + hwsw;
    const size_t gK1 = (size_t)(r0 + 32) * HDIM + hwsw;   // (r0+32)&7 == r0&7
    const size_t gV0 = (size_t)r0 * SEQ + hwsw;
    const size_t gV1 = (size_t)(r0 + 32) * SEQ + hwsw;
    const int ldsW = w * 1024;                            // wave-uniform base
    const int kread = (l31 & 7) << 4;                     // read-side row-XOR (bytes)

    #define STAGE(ti, buf)                                                        \
        do {                                                                      \
            const __bf16* kn = kp + (size_t)(ti) * 64 * HDIM;                     \
            const __bf16* vn = vtp + (size_t)(ti) * 64;                           \
            char* kb = (char*)Ks[buf]; char* vb = (char*)Vs[buf];                 \
            gload16(kn + gK0, kb + ldsW);                                         \
            gload16(kn + gK1, kb + 4096 + ldsW);                                  \
            gload16(vn + gV0, vb + ldsW);                                         \
            gload16(vn + gV1, vb + 4096 + ldsW);                                  \
        } while (0)

    STAGE(0, 0);

    for (int ti = 0; ti < SEQ / 64; ++ti) {
        const int cur = ti & 1;
        __syncthreads();   // drains this wave's vmcnt (buf[cur] ready); prev compute done
        if (ti + 1 < SEQ / 64) STAGE(ti + 1, cur ^ 1);

        const char* kbase = (const char*)Ks[cur];
        const char* vbase = (const char*)Vs[cur];

        // ---- QK^T (swapped): s[key][q], lane owns q=l31 ----
        f32x16 s0, s1;
        #pragma unroll
        for (int r = 0; r < 16; ++r) { s0[r] = 0.f; s1[r] = 0.f; }
        #pragma unroll
        for (int c = 0; c < 4; ++c) {
            const int co = (c * 32 + hi * 16) ^ kread;
            bf16x8 k0 = *reinterpret_cast<const bf16x8*>(kbase + l31 * 128 + co);
            bf16x8 k1 = *reinterpret_cast<const bf16x8*>(kbase + (32 + l31) * 128 + co);
            s0 = mfma32(k0, qf[c], s0);
            s1 = mfma32(k1, qf[c], s1);
        }

        // ---- online softmax (base-2; scale pre-folded into q) ----
        float m0 = fmax3(s0[0],  s0[1],  s0[2]);
        float m1 = fmax3(s0[3],  s0[4],  s0[5]);
        float m2 = fmax3(s0[6],  s0[7],  s0[8]);
        float m3 = fmax3(s0[9],  s0[10], s0[11]);
        float m4 = fmax3(s0[12], s0[13], s0[14]);
        float m5 = fmax3(s0[15], s1[0],  s1[1]);
        float m6 = fmax3(s1[2],  s1[3],  s1[4]);
        float m7 = fmax3(s1[5],  s1[6],  s1[7]);
        float m8 = fmax3(s1[8],  s1[9],  s1[10]);
        float m9 = fmax3(s1[11], s1[12], s1[13]);
        float ma = fmaxf(s1[14], s1[15]);
        float mx = fmax3(fmax3(m0, m1, m2), fmax3(m3, m4, m5),
                         fmax3(fmax3(m6, m7, m8), m9, ma));
        mx = fmaxf(mx, __shfl_xor(mx, 32));   // other 32 keys (paired lane)

        // defer-max (T13): rescale only when tile max grew past threshold
        if (!__all(mx - mrun <= 8.0f)) {
            float mnew = fmaxf(mrun, mx);
            float alpha = fexp2(mrun - mnew);
            mrun = mnew;
            #pragma unroll
            for (int r = 0; r < 16; ++r) {
                int row = (r & 3) + 8 * (r >> 2) + 4 * hi;
                float ar = __shfl(alpha, row);    // alpha lives at lane==q
                oacc[0][r] *= ar; oacc[1][r] *= ar; lacc[r] *= ar;
            }
        }
        const float m = mrun;
        f32x16 e0 = s0 - m;
        f32x16 e1 = s1 - m;
        unsigned pk[16];
        #pragma unroll
        for (int i = 0; i < 8; ++i)
            pk[i] = packbf2(fexp2(e0[2 * i]), fexp2(e0[2 * i + 1]));
        #pragma unroll
        for (int i = 0; i < 8; ++i)
            pk[8 + i] = packbf2(fexp2(e1[2 * i]), fexp2(e1[2 * i + 1]));

        // ---- P -> PV A-frags in-register (permlane32_swap) ----
        bf16x8 pa[4];
        #pragma unroll
        for (int kb = 0; kb < 2; ++kb) {
            uint2v sA = __builtin_amdgcn_permlane32_swap(pk[kb * 8 + 0], pk[kb * 8 + 2], false, false);
            uint2v sB = __builtin_amdgcn_permlane32_swap(pk[kb * 8 + 1], pk[kb * 8 + 3], false, false);
            uint2v sC = __builtin_amdgcn_permlane32_swap(pk[kb * 8 + 4], pk[kb * 8 + 6], false, false);
            uint2v sD = __builtin_amdgcn_permlane32_swap(pk[kb * 8 + 5], pk[kb * 8 + 7], false, false);
            pa[kb * 2 + 0] = fragu(sA[0], sB[0], sA[1], sB[1]);
            pa[kb * 2 + 1] = fragu(sC[0], sD[0], sC[1], sD[1]);
        }

        // ---- O += P V ; denominator via ones-MFMA ----
        #pragma unroll
        for (int db = 0; db < 2; ++db) {
            #pragma unroll
            for (int kc = 0; kc < 4; ++kc) {
                const int co = (kc * 32 + hi * 16) ^ kread;
                bf16x8 vf = *reinterpret_cast<const bf16x8*>(
                    vbase + (db * 32 + l31) * 128 + co);
                oacc[db] = mfma32(pa[kc], vf, oacc[db]);
            }
        }
        #pragma unroll
        for (int kc = 0; kc < 4; ++kc) lacc = mfma32(pa[kc], onesf, lacc);
    }
    #undef STAGE

    // ---- epilogue: normalize, store (B,N,H*D) bf16 ----
    #pragma unroll
    for (int r = 0; r < 16; ++r) {
        int row = (r & 3) + 8 * (r >> 2) + 4 * hi;
        float li = 1.0f / lacc[r];       // lacc[r] = rowsum(q=row), uniform over l31
        int qrow = q0 + w * 32 + row;
        #pragma unroll
        for (int db = 0; db < 2; ++db) {
            int d = h * 64 + db * 32 + l31;
            ao[((size_t)(b * SEQ + qrow)) * FDIM + d] = (__bf16)(oacc[db][r] * li);
        }
    }
}

// ---------------- launcher ----------------
extern "C" void kernel_launch(void* const* d_in, const int* in_sizes, int n_in,
                              void* d_out, int out_size, void* d_ws, size_t ws_size,
                              hipStream_t stream) {
    const float* x    = (const float*)d_in[0];
    const float* Wqkv = (const float*)d_in[1];
    const float* bqkv = (const float*)d_in[2];
    const float* Wfc  = (const float*)d_in[3];
    const float* bfc  = (const float*)d_in[4];
    float* out = (float*)d_out;

    char* ws = (char*)d_ws;
    __bf16* xb    = (__bf16*)(ws + 0);
    __bf16* wqkvt = (__bf16*)(ws + 16777216);
    __bf16* wfct  = (__bf16*)(ws + 23068672);
    __bf16* qb    = (__bf16*)(ws + 25165824);
    __bf16* kb    = (__bf16*)(ws + 41943040);
    __bf16* vb    = (__bf16*)(ws + 58720256);
    __bf16* vtb   = (__bf16*)(ws + 75497472);
    __bf16* aob   = (__bf16*)(ws + 92274688);

    cast_x_kernel<<<8192, 256, 0, stream>>>(x, xb, (MTOT * FDIM) / 4);
    transpose_cast_kernel<<<(3 * FDIM / 64) * (FDIM / 64), 256, 0, stream>>>(Wqkv, wqkvt, FDIM, 3 * FDIM);
    transpose_cast_kernel<<<(FDIM / 64) * (FDIM / 64), 256, 0, stream>>>(Wfc, wfct, FDIM, FDIM);

    gemm_bt_kernel<0><<<(MTOT / 128) * (3 * FDIM / 128), 256, 0, stream>>>(
        xb, wqkvt, bqkv, (void*)qb, MTOT, 3 * FDIM, FDIM, 3 * FDIM / 128);

    transpose_v_kernel<<<BATCH * NHEAD * (SEQ / 64), 256, 0, stream>>>(vb, vtb);

    attn_kernel<<<BATCH * NHEAD * (SEQ / 128), 256, 0, stream>>>(qb, kb, vtb, aob);

    gemm_bt_kernel<1><<<(MTOT / 128) * (FDIM / 128), 256, 0, stream>>>(
        aob, wfct, bfc, (void*)out, MTOT, FDIM, FDIM, FDIM / 128);
}

// Round 4
// 307.292 us; speedup vs baseline: 1.8363x; 1.0569x over previous
//
#include <hip/hip_runtime.h>
#include <hip/hip_bf16.h>

// Fused attention block: qkv = x@Wqkv+b; attn; out = attn_out@Wfc+b
// B=2, N=4096, DIM=1024, H=16, D=64. bf16 MFMA, fp32 accum.

#define SEQ   4096
#define NHEAD 16
#define HDIM  64
#define FDIM  1024
#define BATCH 2
#define MTOT  (BATCH * SEQ)
// 0.125 (1/sqrt(64)) * log2(e): folded into q so softmax runs in base-2 domain.
#define QSCALE 0.1803368801111204f

typedef __attribute__((ext_vector_type(8)))  __bf16 bf16x8;
typedef __attribute__((ext_vector_type(4)))  __bf16 bf16x4;
typedef __attribute__((ext_vector_type(2)))  __bf16 bf16x2;
typedef __attribute__((ext_vector_type(4)))  float  f32x4;
typedef __attribute__((ext_vector_type(16))) float  f32x16;
typedef __attribute__((ext_vector_type(2)))  unsigned uint2v;
typedef __attribute__((ext_vector_type(4)))  unsigned uint4v;

__device__ __forceinline__ f32x4 mfma16(bf16x8 a, bf16x8 b, f32x4 c) {
    return __builtin_amdgcn_mfma_f32_16x16x32_bf16(a, b, c, 0, 0, 0);
}
__device__ __forceinline__ f32x16 mfma32(bf16x8 a, bf16x8 b, f32x16 c) {
    return __builtin_amdgcn_mfma_f32_32x32x16_bf16(a, b, c, 0, 0, 0);
}
__device__ __forceinline__ unsigned packbf2(float lo, float hi) {
    bf16x2 t; t[0] = (__bf16)lo; t[1] = (__bf16)hi;
    return __builtin_bit_cast(unsigned, t);
}
__device__ __forceinline__ bf16x8 fragu(unsigned a, unsigned b, unsigned c, unsigned d) {
    uint4v u = {a, b, c, d};
    return __builtin_bit_cast(bf16x8, u);
}
// raw v_exp_f32: 1 instruction (no denormal-safe expansion)
__device__ __forceinline__ float fexp2(float x) {
    float r; asm("v_exp_f32 %0, %1" : "=v"(r) : "v"(x)); return r;
}
// async global->LDS, 16B/lane; lds must be wave-uniform base (HW adds lane*16)
__device__ __forceinline__ void gload16(const void* g, void* l) {
    __builtin_amdgcn_global_load_lds(
        (const __attribute__((address_space(1))) unsigned*)g,
        (__attribute__((address_space(3))) unsigned*)l, 16, 0, 0);
}
__device__ __forceinline__ float fmax3(float a, float b, float c) {
    return fmaxf(fmaxf(a, b), c);   // clang fuses to v_max3_f32
}

// ---------------- cast x: fp32 -> bf16 ----------------
__global__ __launch_bounds__(256) void cast_x_kernel(const float* __restrict__ in,
                                                     __bf16* __restrict__ out, int n4) {
    int i = blockIdx.x * 256 + threadIdx.x;
    if (i < n4) {
        f32x4 v = reinterpret_cast<const f32x4*>(in)[i];
        bf16x4 o;
        #pragma unroll
        for (int j = 0; j < 4; ++j) o[j] = (__bf16)v[j];
        reinterpret_cast<bf16x4*>(out)[i] = o;
    }
}

// ---------------- transpose + cast W: (K x N) fp32 -> (N x K) bf16 ----------------
__global__ __launch_bounds__(256) void transpose_cast_kernel(const float* __restrict__ in,
                                                             __bf16* __restrict__ out,
                                                             int K, int N) {
    int nbk = K >> 6;
    int bn = blockIdx.x / nbk, bk = blockIdx.x % nbk;
    int n0 = bn * 64, k0 = bk * 64;
    __shared__ __bf16 tile[64][72];
    int t = threadIdx.x;
    #pragma unroll
    for (int p = 0; p < 4; ++p) {
        int c = t + p * 256;
        int kr = c >> 4, nc = (c & 15) * 4;
        f32x4 v = *reinterpret_cast<const f32x4*>(&in[(size_t)(k0 + kr) * N + n0 + nc]);
        #pragma unroll
        for (int j = 0; j < 4; ++j) tile[kr][nc + j] = (__bf16)v[j];
    }
    __syncthreads();
    #pragma unroll
    for (int p = 0; p < 2; ++p) {
        int c = t + p * 256;
        int nr = c >> 3, kc = (c & 7) * 8;
        bf16x8 o;
        #pragma unroll
        for (int j = 0; j < 8; ++j) o[j] = tile[kc + j][nr];
        *reinterpret_cast<bf16x8*>(&out[(size_t)(n0 + nr) * K + k0 + kc]) = o;
    }
}

// ---------------- transpose v: (B,H,N,D) -> (B,H,D,N) bf16 ----------------
__global__ __launch_bounds__(256) void transpose_v_kernel(const __bf16* __restrict__ v,
                                                          __bf16* __restrict__ vt) {
    int bh = blockIdx.x >> 6;
    int n0 = (blockIdx.x & 63) * 64;
    const __bf16* vp = v + (size_t)bh * SEQ * HDIM;
    __bf16* vtp = vt + (size_t)bh * SEQ * HDIM;
    __shared__ __bf16 tile[64][72];
    int t = threadIdx.x;
    #pragma unroll
    for (int p = 0; p < 2; ++p) {
        int c = t + p * 256;
        int r = c >> 3, dch = (c & 7) * 8;
        *reinterpret_cast<bf16x8*>(&tile[r][dch]) =
            *reinterpret_cast<const bf16x8*>(&vp[(size_t)(n0 + r) * HDIM + dch]);
    }
    __syncthreads();
    #pragma unroll
    for (int p = 0; p < 2; ++p) {
        int c = t + p * 256;
        int d = c >> 3, nch = (c & 7) * 8;
        bf16x8 o;
        #pragma unroll
        for (int j = 0; j < 8; ++j) o[j] = tile[nch + j][d];
        *reinterpret_cast<bf16x8*>(&vtp[(size_t)d * SEQ + n0 + nch]) = o;
    }
}

// ---------------- GEMM: C = A(MxK) * Bt(NxK)^T + bias (m97-style staging) ----------------
// MODE 0: scatter bf16 into q/k/v; q gets pre-scaled by QSCALE.
// MODE 1: fp32 output row-major
template <int MODE>
__global__ __launch_bounds__(256) void gemm_bt_kernel(const __bf16* __restrict__ A,
                                                      const __bf16* __restrict__ Bt,
                                                      const float* __restrict__ bias,
                                                      void* __restrict__ out,
                                                      int M, int N, int K, int nbn) {
    int bm = blockIdx.x / nbn, bn = blockIdx.x % nbn;
    int m0 = bm * 128, n0 = bn * 128;
    __shared__ __bf16 As[128 * 32];
    __shared__ __bf16 Bs[128 * 32];
    int t = threadIdx.x, lane = t & 63, w = t >> 6;
    int wr = w >> 1, wc = w & 1;
    int l15 = lane & 15, lk = (lane >> 4) * 8;

    f32x4 acc[4][4] = {};

    // staging geometry: chunk c = p*256 + t; row = c>>2; 8-elem chunk (c&3)
    const int r_c0 = t >> 2, kc_c0 = (t & 3) * 8;          // p=0
    const int r_c1 = (256 + t) >> 2, kc_c1 = (t & 3) * 8;  // p=1 (t&3 unchanged)
    char* AsB = (char*)As; char* BsB = (char*)Bs;
    const int lds0 = w * 1024;          // wave-uniform, p=0
    const int lds1 = 4096 + w * 1024;   // p=1

    for (int kt = 0; kt < K; kt += 32) {
        __syncthreads();
        gload16(&A[(size_t)(m0 + r_c0) * K + kt + kc_c0], AsB + lds0);
        gload16(&A[(size_t)(m0 + r_c1) * K + kt + kc_c1], AsB + lds1);
        gload16(&Bt[(size_t)(n0 + r_c0) * K + kt + kc_c0], BsB + lds0);
        gload16(&Bt[(size_t)(n0 + r_c1) * K + kt + kc_c1], BsB + lds1);
        __syncthreads();
        bf16x8 af[4], bfv[4];
        #pragma unroll
        for (int fm = 0; fm < 4; ++fm)
            af[fm] = *reinterpret_cast<const bf16x8*>(&As[(wr * 64 + fm * 16 + l15) * 32 + lk]);
        #pragma unroll
        for (int fn = 0; fn < 4; ++fn)
            bfv[fn] = *reinterpret_cast<const bf16x8*>(&Bs[(wc * 64 + fn * 16 + l15) * 32 + lk]);
        #pragma unroll
        for (int fm = 0; fm < 4; ++fm)
            #pragma unroll
            for (int fn = 0; fn < 4; ++fn)
                acc[fm][fn] = mfma16(af[fm], bfv[fn], acc[fm][fn]);
    }

    #pragma unroll
    for (int fn = 0; fn < 4; ++fn) {
        int col = n0 + wc * 64 + fn * 16 + l15;
        float bi = bias[col];
        #pragma unroll
        for (int fm = 0; fm < 4; ++fm) {
            f32x4 c = acc[fm][fn];
            #pragma unroll
            for (int r = 0; r < 4; ++r) {
                int row = m0 + wr * 64 + fm * 16 + (lane >> 4) * 4 + r;
                float val = c[r] + bi;
                if (MODE == 0) {
                    int sel = col >> 10, h = (col >> 6) & 15, d = col & 63;
                    int b = row >> 12, nr = row & 4095;
                    if (sel == 0) val *= QSCALE;   // fold attn scale + log2e into q
                    __bf16* qkv = (__bf16*)out;
                    qkv[(size_t)sel * (BATCH * NHEAD * SEQ * HDIM) +
                        ((size_t)(b * NHEAD + h) * SEQ + nr) * HDIM + d] = (__bf16)val;
                } else {
                    ((float*)out)[(size_t)row * N + col] = val;
                }
            }
        }
    }
}

// ---------------- flash attention ----------------
// grid: (B*H) * (SEQ/128); 128 threads = 2 waves; each wave owns 64 q rows
// (2 sub-blocks of 32) so every K/V LDS fragment read feeds 2x the MFMAs.
// Swapped QK^T (lane owns q col). -m folded into the QK accumulator via a
// rank-1 ones x (-m) MFMA with cached negm fragment (rebuilt on rescale only);
// zero-C register hoisted. In-register P via pack+permlane32_swap; denominator
// via ones-MFMA; K/V double-buffered via global_load_lds with pre-swizzled
// global source (linear LDS dest, XOR-swizzled reads).
__global__ __launch_bounds__(128, 2) void attn_kernel(const __bf16* __restrict__ q,
                                                      const __bf16* __restrict__ k,
                                                      const __bf16* __restrict__ vt,
                                                      __bf16* __restrict__ ao) {
    const int bh = blockIdx.x >> 5;
    const int q0 = (blockIdx.x & 31) * 128;
    const int b = bh >> 4, h = bh & 15;
    const __bf16* __restrict__ qp = q + (size_t)bh * SEQ * HDIM;
    const __bf16* __restrict__ kp = k + (size_t)bh * SEQ * HDIM;
    const __bf16* __restrict__ vtp = vt + (size_t)bh * SEQ * HDIM;

    __shared__ __bf16 Ks[2][64 * 64];   // [buf][key][d], 8KB each
    __shared__ __bf16 Vs[2][64 * 64];   // [buf][d][key]

    const int t = threadIdx.x, lane = t & 63, w = t >> 6;
    const int l31 = lane & 31, hi = lane >> 5;

    // Q fragments (B-operand): lane holds Q[q0+w*64+qb*32+l31][c*16+hi*8 .. +8]
    bf16x8 qf[2][4];
    #pragma unroll
    for (int qb = 0; qb < 2; ++qb)
        #pragma unroll
        for (int c = 0; c < 4; ++c)
            qf[qb][c] = *reinterpret_cast<const bf16x8*>(
                &qp[(size_t)(q0 + w * 64 + qb * 32 + l31) * HDIM + c * 16 + hi * 8]);

    f32x16 oacc[2][2], lacc[2];
    #pragma unroll
    for (int qb = 0; qb < 2; ++qb) {
        #pragma unroll
        for (int r = 0; r < 16; ++r) {
            oacc[qb][0][r] = 0.f; oacc[qb][1][r] = 0.f; lacc[qb][r] = 0.f;
        }
    }
    float mrun[2] = {0.f, 0.f};

    // hoisted constants: zero C, ones B-frag (rowsum), ones A-frag (k=0 slot),
    // negm B-frag (k=0 slot carries -mrun; zero until first rescale)
    f32x16 zeroC;
    #pragma unroll
    for (int r = 0; r < 16; ++r) zeroC[r] = 0.f;
    const uint4v onesu = {0x3F803F80u, 0x3F803F80u, 0x3F803F80u, 0x3F803F80u};
    const bf16x8 onesf = __builtin_bit_cast(bf16x8, onesu);
    const bf16x8 onesA = fragu(hi ? 0u : 0x3F80u, 0u, 0u, 0u);
    bf16x8 negmf[2] = {fragu(0u,0u,0u,0u), fragu(0u,0u,0u,0u)};

    // staging: wave w covers rows [w*32, w*32+32) of each tile, 4 gloads each
    const int r8 = lane >> 3;
    const int swz8 = ((lane & 7) ^ r8) * 8;            // pre-swizzled source chunk
    size_t offK[4], offV[4];
    #pragma unroll
    for (int i = 0; i < 4; ++i) {
        int row = w * 32 + i * 8 + r8;
        offK[i] = (size_t)row * HDIM + swz8;
        offV[i] = (size_t)row * SEQ + swz8;
    }
    const int ldsW = w * 4096;                         // wave-uniform base (bytes)
    const int kread = (l31 & 7) << 4;                  // read-side row-XOR (bytes)

    #define STAGE(ti, buf)                                                        \
        do {                                                                      \
            const __bf16* kn = kp + (size_t)(ti) * 64 * HDIM;                     \
            const __bf16* vn = vtp + (size_t)(ti) * 64;                           \
            char* kbuf = (char*)Ks[buf]; char* vbuf = (char*)Vs[buf];             \
            _Pragma("unroll")                                                     \
            for (int i = 0; i < 4; ++i) {                                         \
                gload16(kn + offK[i], kbuf + ldsW + i * 1024);                    \
                gload16(vn + offV[i], vbuf + ldsW + i * 1024);                    \
            }                                                                     \
        } while (0)

    STAGE(0, 0);

    for (int ti = 0; ti < SEQ / 64; ++ti) {
        const int cur = ti & 1;
        __syncthreads();   // drains vmcnt (buf[cur] ready); prev compute done
        if (ti + 1 < SEQ / 64) STAGE(ti + 1, cur ^ 1);

        const char* kbase = (const char*)Ks[cur];
        const char* vbase = (const char*)Vs[cur];

        // ---- QK^T (swapped) + rank-1 (-m) init: s'[key][q] = K.Q - m_old ----
        __builtin_amdgcn_s_setprio(1);
        f32x16 s0q0 = mfma32(onesA, negmf[0], zeroC);
        f32x16 s1q0 = mfma32(onesA, negmf[0], zeroC);
        f32x16 s0q1 = mfma32(onesA, negmf[1], zeroC);
        f32x16 s1q1 = mfma32(onesA, negmf[1], zeroC);
        #pragma unroll
        for (int c = 0; c < 4; ++c) {
            const int co = (c * 32 + hi * 16) ^ kread;
            bf16x8 k0 = *reinterpret_cast<const bf16x8*>(kbase + l31 * 128 + co);
            bf16x8 k1 = *reinterpret_cast<const bf16x8*>(kbase + (32 + l31) * 128 + co);
            s0q0 = mfma32(k0, qf[0][c], s0q0);
            s1q0 = mfma32(k1, qf[0][c], s1q0);
            s0q1 = mfma32(k0, qf[1][c], s0q1);
            s1q1 = mfma32(k1, qf[1][c], s1q1);
        }
        __builtin_amdgcn_s_setprio(0);

        // ---- softmax per q-sub-block ----
        bf16x8 pa[2][4];
        #pragma unroll
        for (int qb = 0; qb < 2; ++qb) {
            f32x16 s0 = qb ? s0q1 : s0q0;
            f32x16 s1 = qb ? s1q1 : s1q0;
            float m0 = fmax3(s0[0],  s0[1],  s0[2]);
            float m1 = fmax3(s0[3],  s0[4],  s0[5]);
            float m2 = fmax3(s0[6],  s0[7],  s0[8]);
            float m3 = fmax3(s0[9],  s0[10], s0[11]);
            float m4 = fmax3(s0[12], s0[13], s0[14]);
            float m5 = fmax3(s0[15], s1[0],  s1[1]);
            float m6 = fmax3(s1[2],  s1[3],  s1[4]);
            float m7 = fmax3(s1[5],  s1[6],  s1[7]);
            float m8 = fmax3(s1[8],  s1[9],  s1[10]);
            float m9 = fmax3(s1[11], s1[12], s1[13]);
            float ma = fmaxf(s1[14], s1[15]);
            float mx = fmax3(fmax3(m0, m1, m2), fmax3(m3, m4, m5),
                             fmax3(fmax3(m6, m7, m8), m9, ma));
            mx = fmaxf(mx, __shfl_xor(mx, 32));   // other 32 keys (paired lane)

            // defer-max (T13): s' already has -m_old folded; rescale iff mx' > 8
            if (!__all(mx <= 8.0f)) {
                float delta = fmaxf(mx, 0.f);
                float alpha = fexp2(-delta);
                mrun[qb] += delta;
                negmf[qb] = fragu(hi ? 0u : packbf2(-mrun[qb], 0.f), 0u, 0u, 0u);
                s0 -= delta;
                s1 -= delta;
                #pragma unroll
                for (int r = 0; r < 16; ++r) {
                    int row = (r & 3) + 8 * (r >> 2) + 4 * hi;
                    float ar = __shfl(alpha, row);    // alpha lives at lane==q
                    oacc[qb][0][r] *= ar; oacc[qb][1][r] *= ar; lacc[qb][r] *= ar;
                }
            }
            unsigned pk[16];
            #pragma unroll
            for (int i = 0; i < 8; ++i)
                pk[i] = packbf2(fexp2(s0[2 * i]), fexp2(s0[2 * i + 1]));
            #pragma unroll
            for (int i = 0; i < 8; ++i)
                pk[8 + i] = packbf2(fexp2(s1[2 * i]), fexp2(s1[2 * i + 1]));

            // P -> PV A-frags in-register (permlane32_swap)
            #pragma unroll
            for (int kb = 0; kb < 2; ++kb) {
                uint2v sA = __builtin_amdgcn_permlane32_swap(pk[kb * 8 + 0], pk[kb * 8 + 2], false, false);
                uint2v sB = __builtin_amdgcn_permlane32_swap(pk[kb * 8 + 1], pk[kb * 8 + 3], false, false);
                uint2v sC = __builtin_amdgcn_permlane32_swap(pk[kb * 8 + 4], pk[kb * 8 + 6], false, false);
                uint2v sD = __builtin_amdgcn_permlane32_swap(pk[kb * 8 + 5], pk[kb * 8 + 7], false, false);
                pa[qb][kb * 2 + 0] = fragu(sA[0], sB[0], sA[1], sB[1]);
                pa[qb][kb * 2 + 1] = fragu(sC[0], sD[0], sC[1], sD[1]);
            }
        }

        // ---- O += P V ; denominator via ones-MFMA (V frag read serves both qb) ----
        __builtin_amdgcn_s_setprio(1);
        #pragma unroll
        for (int kc = 0; kc < 4; ++kc) {
            const int co = (kc * 32 + hi * 16) ^ kread;
            #pragma unroll
            for (int db = 0; db < 2; ++db) {
                bf16x8 vf = *reinterpret_cast<const bf16x8*>(
                    vbase + (db * 32 + l31) * 128 + co);
                oacc[0][db] = mfma32(pa[0][kc], vf, oacc[0][db]);
                oacc[1][db] = mfma32(pa[1][kc], vf, oacc[1][db]);
            }
            lacc[0] = mfma32(pa[0][kc], onesf, lacc[0]);
            lacc[1] = mfma32(pa[1][kc], onesf, lacc[1]);
        }
        __builtin_amdgcn_s_setprio(0);
    }
    #undef STAGE

    // ---- epilogue: normalize, store (B,N,H*D) bf16 ----
    #pragma unroll
    for (int qb = 0; qb < 2; ++qb) {
        #pragma unroll
        for (int r = 0; r < 16; ++r) {
            int row = (r & 3) + 8 * (r >> 2) + 4 * hi;
            float li = 1.0f / lacc[qb][r];   // rowsum(q=row), uniform over l31
            int qrow = q0 + w * 64 + qb * 32 + row;
            #pragma unroll
            for (int db = 0; db < 2; ++db) {
                int d = h * 64 + db * 32 + l31;
                ao[((size_t)(b * SEQ + qrow)) * FDIM + d] = (__bf16)(oacc[qb][db][r] * li);
            }
        }
    }
}

// ---------------- launcher ----------------
extern "C" void kernel_launch(void* const* d_in, const int* in_sizes, int n_in,
                              void* d_out, int out_size, void* d_ws, size_t ws_size,
                              hipStream_t stream) {
    const float* x    = (const float*)d_in[0];
    const float* Wqkv = (const float*)d_in[1];
    const float* bqkv = (const float*)d_in[2];
    const float* Wfc  = (const float*)d_in[3];
    const float* bfc  = (const float*)d_in[4];
    float* out = (float*)d_out;

    char* ws = (char*)d_ws;
    __bf16* xb    = (__bf16*)(ws + 0);
    __bf16* wqkvt = (__bf16*)(ws + 16777216);
    __bf16* wfct  = (__bf16*)(ws + 23068672);
    __bf16* qb    = (__bf16*)(ws + 25165824);
    __bf16* kb    = (__bf16*)(ws + 41943040);
    __bf16* vb    = (__bf16*)(ws + 58720256);
    __bf16* vtb   = (__bf16*)(ws + 75497472);
    __bf16* aob   = (__bf16*)(ws + 92274688);

    cast_x_kernel<<<8192, 256, 0, stream>>>(x, xb, (MTOT * FDIM) / 4);
    transpose_cast_kernel<<<(3 * FDIM / 64) * (FDIM / 64), 256, 0, stream>>>(Wqkv, wqkvt, FDIM, 3 * FDIM);
    transpose_cast_kernel<<<(FDIM / 64) * (FDIM / 64), 256, 0, stream>>>(Wfc, wfct, FDIM, FDIM);

    gemm_bt_kernel<0><<<(MTOT / 128) * (3 * FDIM / 128), 256, 0, stream>>>(
        xb, wqkvt, bqkv, (void*)qb, MTOT, 3 * FDIM, FDIM, 3 * FDIM / 128);

    transpose_v_kernel<<<BATCH * NHEAD * (SEQ / 64), 256, 0, stream>>>(vb, vtb);

    attn_kernel<<<BATCH * NHEAD * (SEQ / 128), 128, 0, stream>>>(qb, kb, vtb, aob);

    gemm_bt_kernel<1><<<(MTOT / 128) * (FDIM / 128), 256, 0, stream>>>(
        aob, wfct, bfc, (void*)out, MTOT, FDIM, FDIM, FDIM / 128);
}